// Round 15
// baseline (1056.840 us; speedup 1.0000x reference)
//
#include <hip/hip_runtime.h>
#include <cmath>

#define BB   64
#define SEQ  1024
#define DD   256
#define HH   32
#define G4   128   // 4*H
#define VV   2048

// fast sigmoid: e^x/(1+e^x) = 1 - 1/(1+e^x)
__device__ __forceinline__ float fsigm(float x) {
    return 1.0f - __builtin_amdgcn_rcpf(1.0f + __expf(x));
}
// fast tanh: 1 - 2/(1+e^(2x))
__device__ __forceinline__ float ftanh(float x) {
    return 1.0f - 2.0f * __builtin_amdgcn_rcpf(1.0f + __expf(2.0f * x));
}

// y[l] = x[l^32] via v_permlane32_swap (verified r10). With old=src=x:
// r[0]=[x_lo|x_lo], r[1]=[x_hi|x_hi]; lane<32 wants x_hi -> r[1], lane>=32 -> r[0].
__device__ __forceinline__ float lane_xor32(float x, int half) {
#if __has_builtin(__builtin_amdgcn_permlane32_swap)
    auto r = __builtin_amdgcn_permlane32_swap(__float_as_uint(x), __float_as_uint(x),
                                              false, false);
    return __uint_as_float(half ? r[0] : r[1]);
#else
    return __shfl_xor(x, 32, 64);
#endif
}

#define FMA4F(A, W, H) \
    A = fmaf((W).w, (H).w, fmaf((W).z, (H).z, fmaf((W).y, (H).y, fmaf((W).x, (H).x, A))))

// ---------------------------------------------------------------------------
// Kernel A1: emb_proj[v][j] = b_ih1[j]+b_hh1[j] + sum_d emb[v][d]*W_ih1[j][d]
// ---------------------------------------------------------------------------
__global__ __launch_bounds__(128) void emb_proj_kernel(
    const float* __restrict__ emb, const float* __restrict__ W_ih1,
    const float* __restrict__ b_ih1, const float* __restrict__ b_hh1,
    float* __restrict__ emb_proj)
{
    const int v = blockIdx.x;
    const int j = threadIdx.x;
    __shared__ __align__(16) float ev[DD];
    ev[j]       = emb[v * DD + j];
    ev[j + 128] = emb[v * DD + 128 + j];
    __syncthreads();
    float acc = b_ih1[j] + b_hh1[j];
#pragma unroll 8
    for (int q = 0; q < DD / 4; ++q) {
        float4 w = *(const float4*)&W_ih1[j * DD + 4 * q];
        float4 e = *(const float4*)&ev[4 * q];
        acc += w.x * e.x + w.y * e.y + w.z * e.z + w.w * e.w;
    }
    emb_proj[v * G4 + j] = acc;
}

// ---------------------------------------------------------------------------
// Kernel A2: W_fcT[k][v] = W_fc[v][k]
// ---------------------------------------------------------------------------
__global__ __launch_bounds__(256) void transpose_wfc_kernel(
    const float* __restrict__ W_fc, float* __restrict__ W_fcT)
{
    int i = blockIdx.x * 256 + threadIdx.x;
    int v = i >> 5;
    int k = i & 31;
    W_fcT[k * VV + v] = W_fc[i];
}

// ---------------------------------------------------------------------------
// Kernel B: 2-wave producer-consumer LSTM. One block (128 thr) per batch.
// Wave 0 = layer 1 (r10 2-rows/lane layout, recurrence fully wave-internal:
// LDS round trip + lgkmcnt, NO barrier). Wave 1 = layer 2, lagging, consumes
// h1 via a 4-deep LDS ring. Sync = monotone LDS flags (volatile) + compiler
// fences; flag reads cached so the spin is skipped most steps. r13/r14's
// per-step s_barrier (~600cy arrive/release with 4 waves) is GONE.
// W_ih2 lives in LDS (r12 quad-transposed, conflict-free) to keep both
// waves' VGPR demand under the allocator's ~140 cap (r5-r11 lesson).
// ---------------------------------------------------------------------------
__global__ __launch_bounds__(128) void lstm_rec_pc_kernel(
    const int* __restrict__ x_ids, const float* __restrict__ emb_proj,
    const float* __restrict__ W_hh1, const float* __restrict__ W_ih2,
    const float* __restrict__ W_hh2, const float* __restrict__ b_ih2,
    const float* __restrict__ b_hh2, float* __restrict__ h2_all)
{
    const int tid = threadIdx.x;
    const int b   = blockIdx.x;
    const int wid = tid >> 6;          // 0 = layer1, 1 = layer2
    const int l   = tid & 63;
    const int half = l >> 5;
    const int r0 = l;
    const int r1 = l + 64;

    // r0 rows (i or f): sigmoid. r1 rows: g (tanh) on half0, o (sigm) on half1.
    const float a1  = half ? 1.0f : 2.0f;
    const float c1p = half ? 1.0f : 2.0f;

    __shared__ __align__(16) float4 T2[8 * 128];   // W_ih2 quad-transposed (16KB)
    __shared__ __align__(16) float h1ring[4][HH];  // h1(t) at slot t&3
    __shared__ __align__(16) float h2buf[2][HH];   // h2(s) at slot s&1
    __shared__ int flags[2];                       // [0]=l1_done, [1]=l2_done
    volatile int* vfl = flags;

    // stage W_ih2: T2[q*128+row] = W_ih2[row][4q..4q+3] (conflict-free reads)
    {
        const float4* src = (const float4*)W_ih2;  // [128][8] quads
        for (int i = tid; i < 1024; i += 128) {
            const int q = i >> 7, row = i & 127;
            T2[i] = src[row * 8 + q];
        }
    }
    if (tid == 0) { flags[0] = 0; flags[1] = 0; }
    if (tid < HH) { h1ring[3][tid] = 0.0f; h2buf[1][tid] = 0.0f; }
    __syncthreads();   // once, before the loop

    if (wid == 0) {
        // ================= layer 1 wave =================
        float4 w0,w1,w2,w3,w4,w5,w6,w7, x0,x1,x2,x3,x4,x5,x6,x7;
        {
            const float4* pw = (const float4*)&W_hh1[r0 * HH];
            w0=pw[0]; w1=pw[1]; w2=pw[2]; w3=pw[3];
            w4=pw[4]; w5=pw[5]; w6=pw[6]; w7=pw[7];
            const float4* px = (const float4*)&W_hh1[r1 * HH];
            x0=px[0]; x1=px[1]; x2=px[2]; x3=px[3];
            x4=px[4]; x5=px[5]; x6=px[6]; x7=px[7];
        }
        const int* ids = x_ids + b * SEQ;
        int idn = ids[1];
        float ep0 = emb_proj[ids[0] * G4 + r0];
        float ep1 = emb_proj[ids[0] * G4 + r1];
        float c1 = 0.0f;
        int l2cache = 0;

        for (int t = 0; t < SEQ; ++t) {
            const float ep0n = emb_proj[idn * G4 + r0];
            const float ep1n = emb_proj[idn * G4 + r1];
            const int tn2 = (t + 2 < SEQ) ? (t + 2) : (SEQ - 1);
            const int idn2 = ids[tn2];

            // dot: W_hh1 rows r0,r1 . h1(t-1)  (r10 grouping)
            const float4* hv = (const float4*)h1ring[(t + 3) & 3];
            float a0=0.f,ae1=0.f,a2=0.f,a3=0.f, bq0=0.f,bq1=0.f,bq2=0.f,bq3=0.f;
            float4 hq;
            hq=hv[0]; FMA4F(a0 ,w0,hq); FMA4F(bq0,x0,hq);
            hq=hv[1]; FMA4F(ae1,w1,hq); FMA4F(bq1,x1,hq);
            hq=hv[2]; FMA4F(a2 ,w2,hq); FMA4F(bq2,x2,hq);
            hq=hv[3]; FMA4F(a3 ,w3,hq); FMA4F(bq3,x3,hq);
            hq=hv[4]; FMA4F(a0 ,w4,hq); FMA4F(bq0,x4,hq);
            hq=hv[5]; FMA4F(ae1,w5,hq); FMA4F(bq1,x5,hq);
            hq=hv[6]; FMA4F(a2 ,w6,hq); FMA4F(bq2,x6,hq);
            hq=hv[7]; FMA4F(a3 ,w7,hq); FMA4F(bq3,x7,hq);
            const float gr0 = ep0 + ((a0 + ae1) + (a2 + a3));
            const float gr1 = ep1 + ((bq0 + bq1) + (bq2 + bq3));

            const float A0 = fsigm(gr0);
            const float A1 = 1.0f - c1p * __builtin_amdgcn_rcpf(1.0f + __expf(a1 * gr1));
            const float B0 = lane_xor32(A0, half);
            const float B1 = lane_xor32(A1, half);
            const float gi = half ? B0 : A0;
            const float gf = half ? A0 : B0;
            const float gg = half ? B1 : A1;
            const float go = half ? A1 : B1;

            c1 = gf * c1 + gi * gg;
            const float h1n = go * ftanh(c1);

            // ring-slot guard: writing slot t&3 overwrites h1(t-4), consumed
            // by L2 at s=t-4 -> need l2_done >= t-3 (monotone; cached)
            if (t >= 4) {
                const int need = t - 3;
                while (l2cache < need) {
                    l2cache = vfl[1];
                    if (l2cache >= need) break;
                    __builtin_amdgcn_s_sleep(1);
                }
            }
            asm volatile("" ::: "memory");
            if (l < HH) h1ring[t & 3][l] = h1n;
            asm volatile("s_waitcnt lgkmcnt(0)" ::: "memory");
            if (l == 0) vfl[0] = t + 1;

            ep0 = ep0n; ep1 = ep1n; idn = idn2;
        }
    } else {
        // ================= layer 2 wave =================
        float4 v0,v1,v2,v3,v4,v5,v6,v7, y0,y1,y2,y3,y4,y5,y6,y7;
        {
            const float4* pv = (const float4*)&W_hh2[r0 * HH];
            v0=pv[0]; v1=pv[1]; v2=pv[2]; v3=pv[3];
            v4=pv[4]; v5=pv[5]; v6=pv[6]; v7=pv[7];
            const float4* py = (const float4*)&W_hh2[r1 * HH];
            y0=py[0]; y1=py[1]; y2=py[2]; y3=py[3];
            y4=py[4]; y5=py[5]; y6=py[6]; y7=py[7];
        }
        const float bias20 = b_ih2[r0] + b_hh2[r0];
        const float bias21 = b_ih2[r1] + b_hh2[r1];
        float c2 = 0.0f;
        float* h2out = h2_all + (long)b * SEQ * HH;
        int l1cache = 0;

        for (int s = 0; s < SEQ; ++s) {
            // wait for h1(s)
            const int need = s + 1;
            while (l1cache < need) {
                l1cache = vfl[0];
                if (l1cache >= need) break;
                __builtin_amdgcn_s_sleep(1);
            }
            asm volatile("" ::: "memory");

            const float4* h1v = (const float4*)h1ring[s & 3];
            const float4* h2v = (const float4*)h2buf[(s + 1) & 1];

            // e = W_ih2 (LDS, conflict-free) . h1(s);  p = W_hh2 (regs) . h2(s-1)
            float ea0=0.f,ea1=0.f,ea2=0.f,ea3=0.f, eb0=0.f,eb1=0.f,eb2=0.f,eb3=0.f;
            float pa0=0.f,pa1=0.f,pa2=0.f,pa3=0.f, pb0=0.f,pb1=0.f,pb2=0.f,pb3=0.f;
            float4 hq, wq;
            hq=h1v[0]; wq=T2[0*128+r0]; FMA4F(ea0,wq,hq); wq=T2[0*128+r1]; FMA4F(eb0,wq,hq);
            hq=h1v[1]; wq=T2[1*128+r0]; FMA4F(ea1,wq,hq); wq=T2[1*128+r1]; FMA4F(eb1,wq,hq);
            hq=h1v[2]; wq=T2[2*128+r0]; FMA4F(ea2,wq,hq); wq=T2[2*128+r1]; FMA4F(eb2,wq,hq);
            hq=h1v[3]; wq=T2[3*128+r0]; FMA4F(ea3,wq,hq); wq=T2[3*128+r1]; FMA4F(eb3,wq,hq);
            hq=h1v[4]; wq=T2[4*128+r0]; FMA4F(ea0,wq,hq); wq=T2[4*128+r1]; FMA4F(eb0,wq,hq);
            hq=h1v[5]; wq=T2[5*128+r0]; FMA4F(ea1,wq,hq); wq=T2[5*128+r1]; FMA4F(eb1,wq,hq);
            hq=h1v[6]; wq=T2[6*128+r0]; FMA4F(ea2,wq,hq); wq=T2[6*128+r1]; FMA4F(eb2,wq,hq);
            hq=h1v[7]; wq=T2[7*128+r0]; FMA4F(ea3,wq,hq); wq=T2[7*128+r1]; FMA4F(eb3,wq,hq);
            hq=h2v[0]; FMA4F(pa0,v0,hq); FMA4F(pb0,y0,hq);
            hq=h2v[1]; FMA4F(pa1,v1,hq); FMA4F(pb1,y1,hq);
            hq=h2v[2]; FMA4F(pa2,v2,hq); FMA4F(pb2,y2,hq);
            hq=h2v[3]; FMA4F(pa3,v3,hq); FMA4F(pb3,y3,hq);
            hq=h2v[4]; FMA4F(pa0,v4,hq); FMA4F(pb0,y4,hq);
            hq=h2v[5]; FMA4F(pa1,v5,hq); FMA4F(pb1,y5,hq);
            hq=h2v[6]; FMA4F(pa2,v6,hq); FMA4F(pb2,y6,hq);
            hq=h2v[7]; FMA4F(pa3,v7,hq); FMA4F(pb3,y7,hq);
            const float e0 = (ea0 + ea1) + (ea2 + ea3);
            const float e1 = (eb0 + eb1) + (eb2 + eb3);
            const float p0 = (pa0 + pa1) + (pa2 + pa3);
            const float p1 = (pb0 + pb1) + (pb2 + pb3);
            const float qr0 = bias20 + p0 + e0;
            const float qr1 = bias21 + p1 + e1;

            const float C0 = fsigm(qr0);
            const float C1 = 1.0f - c1p * __builtin_amdgcn_rcpf(1.0f + __expf(a1 * qr1));
            const float D0 = lane_xor32(C0, half);
            const float D1 = lane_xor32(C1, half);
            const float pi = half ? D0 : C0;
            const float pf = half ? C0 : D0;
            const float pg = half ? D1 : C1;
            const float po = half ? C1 : D1;

            c2 = pf * c2 + pi * pg;
            const float h2n = po * ftanh(c2);

            if (l < HH) {
                h2buf[s & 1][l] = h2n;
                h2out[(long)s * HH + l] = h2n;
            }
            asm volatile("s_waitcnt lgkmcnt(0)" ::: "memory");
            if (l == 0) vfl[1] = s + 1;
        }
    }
}

// ---------------------------------------------------------------------------
// Kernel C: logits = h2 @ W_fc^T + b_fc, row softmax, write [B*S][V].
// r1/r11-proven config: 8 rows/block, 256 threads, 8 vocab cols/thread.
// ---------------------------------------------------------------------------
__global__ __launch_bounds__(256) void fc_softmax_kernel(
    const float* __restrict__ h2_all, const float* __restrict__ W_fcT,
    const float* __restrict__ b_fc, float* __restrict__ out)
{
    const int tid = threadIdx.x;
    const long rowbase = (long)blockIdx.x * 8;
    __shared__ __align__(16) float h2t[8][HH];
    __shared__ float wred[8][4];

    h2t[tid >> 5][tid & 31] = h2_all[rowbase * HH + tid];
    __syncthreads();

    const int v0 = tid * 8;
    const float4 bf0 = *(const float4*)&b_fc[v0];
    const float4 bf1 = *(const float4*)&b_fc[v0 + 4];
    float acc[8][8];
#pragma unroll
    for (int r = 0; r < 8; ++r) {
        acc[r][0] = bf0.x; acc[r][1] = bf0.y; acc[r][2] = bf0.z; acc[r][3] = bf0.w;
        acc[r][4] = bf1.x; acc[r][5] = bf1.y; acc[r][6] = bf1.z; acc[r][7] = bf1.w;
    }

#pragma unroll
    for (int kq = 0; kq < 8; ++kq) {
        const int k = kq * 4;
        float4 wa[4], wb[4];
#pragma unroll
        for (int i = 0; i < 4; ++i) {
            wa[i] = *(const float4*)&W_fcT[(k + i) * VV + v0];
            wb[i] = *(const float4*)&W_fcT[(k + i) * VV + v0 + 4];
        }
#pragma unroll
        for (int r = 0; r < 8; ++r) {
            const float4 h = *(const float4*)&h2t[r][k];
            const float hh[4] = {h.x, h.y, h.z, h.w};
#pragma unroll
            for (int i = 0; i < 4; ++i) {
                acc[r][0] += hh[i] * wa[i].x; acc[r][1] += hh[i] * wa[i].y;
                acc[r][2] += hh[i] * wa[i].z; acc[r][3] += hh[i] * wa[i].w;
                acc[r][4] += hh[i] * wb[i].x; acc[r][5] += hh[i] * wb[i].y;
                acc[r][6] += hh[i] * wb[i].z; acc[r][7] += hh[i] * wb[i].w;
            }
        }
    }

    const int wv = tid >> 6;
    const int lane = tid & 63;

    float m[8];
#pragma unroll
    for (int r = 0; r < 8; ++r) {
        float v = acc[r][0];
#pragma unroll
        for (int c = 1; c < 8; ++c) v = fmaxf(v, acc[r][c]);
#pragma unroll
        for (int s = 32; s >= 1; s >>= 1) v = fmaxf(v, __shfl_xor(v, s, 64));
        m[r] = v;
    }
    if (lane == 0) {
#pragma unroll
        for (int r = 0; r < 8; ++r) wred[r][wv] = m[r];
    }
    __syncthreads();
    float rm[8];
#pragma unroll
    for (int r = 0; r < 8; ++r)
        rm[r] = fmaxf(fmaxf(wred[r][0], wred[r][1]), fmaxf(wred[r][2], wred[r][3]));
    __syncthreads();

    float s[8];
#pragma unroll
    for (int r = 0; r < 8; ++r) {
        float sum = 0.0f;
#pragma unroll
        for (int c = 0; c < 8; ++c) {
            float e = __expf(acc[r][c] - rm[r]);
            acc[r][c] = e;
            sum += e;
        }
#pragma unroll
        for (int st = 32; st >= 1; st >>= 1) sum += __shfl_xor(sum, st, 64);
        s[r] = sum;
    }
    if (lane == 0) {
#pragma unroll
        for (int r = 0; r < 8; ++r) wred[r][wv] = s[r];
    }
    __syncthreads();

#pragma unroll
    for (int r = 0; r < 8; ++r) {
        const float rs = wred[r][0] + wred[r][1] + wred[r][2] + wred[r][3];
        const float inv = 1.0f / rs;
        float4 o0 = make_float4(acc[r][0] * inv, acc[r][1] * inv, acc[r][2] * inv, acc[r][3] * inv);
        float4 o1 = make_float4(acc[r][4] * inv, acc[r][5] * inv, acc[r][6] * inv, acc[r][7] * inv);
        float* op = out + (rowbase + r) * VV + v0;
        *(float4*)op = o0;
        *(float4*)(op + 4) = o1;
    }
}

// ---------------------------------------------------------------------------
extern "C" void kernel_launch(void* const* d_in, const int* in_sizes, int n_in,
                              void* d_out, int out_size, void* d_ws, size_t ws_size,
                              hipStream_t stream)
{
    const int*   x_ids = (const int*)d_in[0];
    const float* emb   = (const float*)d_in[1];
    const float* W_ih1 = (const float*)d_in[2];
    const float* W_hh1 = (const float*)d_in[3];
    const float* b_ih1 = (const float*)d_in[4];
    const float* b_hh1 = (const float*)d_in[5];
    const float* W_ih2 = (const float*)d_in[6];
    const float* W_hh2 = (const float*)d_in[7];
    const float* b_ih2 = (const float*)d_in[8];
    const float* b_hh2 = (const float*)d_in[9];
    const float* W_fc  = (const float*)d_in[10];
    const float* b_fc  = (const float*)d_in[11];
    float* out = (float*)d_out;

    float* ws = (float*)d_ws;
    float* emb_proj = ws;                         // V*4H   = 262144
    float* W_fcT    = ws + 262144;                // H*V    = 65536
    float* h2_all   = ws + 262144 + 65536;        // B*S*H  = 2097152

    emb_proj_kernel<<<VV, 128, 0, stream>>>(emb, W_ih1, b_ih1, b_hh1, emb_proj);
    transpose_wfc_kernel<<<(VV * HH) / 256, 256, 0, stream>>>(W_fc, W_fcT);
    lstm_rec_pc_kernel<<<BB, 128, 0, stream>>>(x_ids, emb_proj, W_hh1, W_ih2, W_hh2,
                                               b_ih2, b_hh2, h2_all);
    fc_softmax_kernel<<<(BB * SEQ) / 8, 256, 0, stream>>>(h2_all, W_fcT, b_fc, out);
}

// Round 16
// 1039.647 us; speedup vs baseline: 1.0165x; 1.0165x over previous
//
#include <hip/hip_runtime.h>
#include <cmath>

#define BB   64
#define SEQ  1024
#define DD   256
#define HH   32
#define G4   128   // 4*H
#define VV   2048
#define RING 32    // h1 ring depth: L1 may run up to RING-1 steps ahead of L2

// fast sigmoid: e^x/(1+e^x) = 1 - 1/(1+e^x)
__device__ __forceinline__ float fsigm(float x) {
    return 1.0f - __builtin_amdgcn_rcpf(1.0f + __expf(x));
}
// fast tanh: 1 - 2/(1+e^(2x))
__device__ __forceinline__ float ftanh(float x) {
    return 1.0f - 2.0f * __builtin_amdgcn_rcpf(1.0f + __expf(2.0f * x));
}

// y[l] = x[l^32] via v_permlane32_swap (verified r10). With old=src=x:
// r[0]=[x_lo|x_lo], r[1]=[x_hi|x_hi]; lane<32 wants x_hi -> r[1], lane>=32 -> r[0].
__device__ __forceinline__ float lane_xor32(float x, int half) {
#if __has_builtin(__builtin_amdgcn_permlane32_swap)
    auto r = __builtin_amdgcn_permlane32_swap(__float_as_uint(x), __float_as_uint(x),
                                              false, false);
    return __uint_as_float(half ? r[0] : r[1]);
#else
    return __shfl_xor(x, 32, 64);
#endif
}

#define FMA4F(A, W, H) \
    A = fmaf((W).w, (H).w, fmaf((W).z, (H).z, fmaf((W).y, (H).y, fmaf((W).x, (H).x, A))))

// ---------------------------------------------------------------------------
// Kernel A1: emb_proj[v][j] = b_ih1[j]+b_hh1[j] + sum_d emb[v][d]*W_ih1[j][d]
// ---------------------------------------------------------------------------
__global__ __launch_bounds__(128) void emb_proj_kernel(
    const float* __restrict__ emb, const float* __restrict__ W_ih1,
    const float* __restrict__ b_ih1, const float* __restrict__ b_hh1,
    float* __restrict__ emb_proj)
{
    const int v = blockIdx.x;
    const int j = threadIdx.x;
    __shared__ __align__(16) float ev[DD];
    ev[j]       = emb[v * DD + j];
    ev[j + 128] = emb[v * DD + 128 + j];
    __syncthreads();
    float acc = b_ih1[j] + b_hh1[j];
#pragma unroll 8
    for (int q = 0; q < DD / 4; ++q) {
        float4 w = *(const float4*)&W_ih1[j * DD + 4 * q];
        float4 e = *(const float4*)&ev[4 * q];
        acc += w.x * e.x + w.y * e.y + w.z * e.z + w.w * e.w;
    }
    emb_proj[v * G4 + j] = acc;
}

// ---------------------------------------------------------------------------
// Kernel A2: W_fcT[k][v] = W_fc[v][k]
// ---------------------------------------------------------------------------
__global__ __launch_bounds__(256) void transpose_wfc_kernel(
    const float* __restrict__ W_fc, float* __restrict__ W_fcT)
{
    int i = blockIdx.x * 256 + threadIdx.x;
    int v = i >> 5;
    int k = i & 31;
    W_fcT[k * VV + v] = W_fc[i];
}

// ---------------------------------------------------------------------------
// Kernel B: 2-wave producer-consumer LSTM, DEEP-RING edition.
// r15's ring depth 4 over-coupled the waves (L1 <= 3 ahead -> L1 blocked on
// L2's completion every step -> fully serial, 852us = r12's serial rate).
// RING=32 lets L1 build a ~30-step lead: flag reads amortize over ~28 steps,
// handshake leaves the critical path, rate -> max(L1 span, L2 span).
// ---------------------------------------------------------------------------
__global__ __launch_bounds__(128) void lstm_rec_pc_kernel(
    const int* __restrict__ x_ids, const float* __restrict__ emb_proj,
    const float* __restrict__ W_hh1, const float* __restrict__ W_ih2,
    const float* __restrict__ W_hh2, const float* __restrict__ b_ih2,
    const float* __restrict__ b_hh2, float* __restrict__ h2_all)
{
    const int tid = threadIdx.x;
    const int b   = blockIdx.x;
    const int wid = tid >> 6;          // 0 = layer1, 1 = layer2
    const int l   = tid & 63;
    const int half = l >> 5;
    const int r0 = l;
    const int r1 = l + 64;

    // r0 rows (i or f): sigmoid. r1 rows: g (tanh) on half0, o (sigm) on half1.
    const float a1  = half ? 1.0f : 2.0f;
    const float c1p = half ? 1.0f : 2.0f;

    __shared__ __align__(16) float4 T2[8 * 128];      // W_ih2 quad-transposed (16KB)
    __shared__ __align__(16) float h1ring[RING][HH];  // h1(t) at slot t&(RING-1)
    __shared__ __align__(16) float h2buf[2][HH];      // h2(s) at slot s&1
    __shared__ int flags[2];                          // [0]=l1_done, [1]=l2_done
    volatile int* vfl = flags;

    // stage W_ih2: T2[q*128+row] = W_ih2[row][4q..4q+3] (conflict-free reads)
    {
        const float4* src = (const float4*)W_ih2;  // [128][8] quads
        for (int i = tid; i < 1024; i += 128) {
            const int q = i >> 7, row = i & 127;
            T2[i] = src[row * 8 + q];
        }
    }
    if (tid == 0) { flags[0] = 0; flags[1] = 0; }
    if (tid < HH) { h1ring[RING - 1][tid] = 0.0f; h2buf[1][tid] = 0.0f; }
    __syncthreads();   // once, before the loop

    if (wid == 0) {
        // ================= layer 1 wave =================
        float4 w0,w1,w2,w3,w4,w5,w6,w7, x0,x1,x2,x3,x4,x5,x6,x7;
        {
            const float4* pw = (const float4*)&W_hh1[r0 * HH];
            w0=pw[0]; w1=pw[1]; w2=pw[2]; w3=pw[3];
            w4=pw[4]; w5=pw[5]; w6=pw[6]; w7=pw[7];
            const float4* px = (const float4*)&W_hh1[r1 * HH];
            x0=px[0]; x1=px[1]; x2=px[2]; x3=px[3];
            x4=px[4]; x5=px[5]; x6=px[6]; x7=px[7];
        }
        const int* ids = x_ids + b * SEQ;
        int idn = ids[1];
        float ep0 = emb_proj[ids[0] * G4 + r0];
        float ep1 = emb_proj[ids[0] * G4 + r1];
        float c1 = 0.0f;
        int l2cache = 0;

        for (int t = 0; t < SEQ; ++t) {
            const float ep0n = emb_proj[idn * G4 + r0];
            const float ep1n = emb_proj[idn * G4 + r1];
            const int tn2 = (t + 2 < SEQ) ? (t + 2) : (SEQ - 1);
            const int idn2 = ids[tn2];

            // dot: W_hh1 rows r0,r1 . h1(t-1)  (r10 grouping)
            const float4* hv = (const float4*)h1ring[(t + RING - 1) & (RING - 1)];
            float a0=0.f,ae1=0.f,a2=0.f,a3=0.f, bq0=0.f,bq1=0.f,bq2=0.f,bq3=0.f;
            float4 hq;
            hq=hv[0]; FMA4F(a0 ,w0,hq); FMA4F(bq0,x0,hq);
            hq=hv[1]; FMA4F(ae1,w1,hq); FMA4F(bq1,x1,hq);
            hq=hv[2]; FMA4F(a2 ,w2,hq); FMA4F(bq2,x2,hq);
            hq=hv[3]; FMA4F(a3 ,w3,hq); FMA4F(bq3,x3,hq);
            hq=hv[4]; FMA4F(a0 ,w4,hq); FMA4F(bq0,x4,hq);
            hq=hv[5]; FMA4F(ae1,w5,hq); FMA4F(bq1,x5,hq);
            hq=hv[6]; FMA4F(a2 ,w6,hq); FMA4F(bq2,x6,hq);
            hq=hv[7]; FMA4F(a3 ,w7,hq); FMA4F(bq3,x7,hq);
            const float gr0 = ep0 + ((a0 + ae1) + (a2 + a3));
            const float gr1 = ep1 + ((bq0 + bq1) + (bq2 + bq3));

            const float A0 = fsigm(gr0);
            const float A1 = 1.0f - c1p * __builtin_amdgcn_rcpf(1.0f + __expf(a1 * gr1));
            const float B0 = lane_xor32(A0, half);
            const float B1 = lane_xor32(A1, half);
            const float gi = half ? B0 : A0;
            const float gf = half ? A0 : B0;
            const float gg = half ? B1 : A1;
            const float go = half ? A1 : B1;

            c1 = gf * c1 + gi * gg;
            const float h1n = go * ftanh(c1);

            // ring-slot guard: writing slot t&(R-1) overwrites h1(t-R),
            // consumed by L2 at s=t-R -> need l2_done >= t-R+1 (rare wait)
            if (t >= RING) {
                const int need = t - (RING - 1);
                while (l2cache < need) {
                    l2cache = vfl[1];
                    if (l2cache >= need) break;
                    __builtin_amdgcn_s_sleep(1);
                }
            }
            asm volatile("" ::: "memory");
            if (l < HH) h1ring[t & (RING - 1)][l] = h1n;
            asm volatile("s_waitcnt lgkmcnt(0)" ::: "memory");
            if (l == 0) vfl[0] = t + 1;

            ep0 = ep0n; ep1 = ep1n; idn = idn2;
        }
    } else {
        // ================= layer 2 wave =================
        float4 v0,v1,v2,v3,v4,v5,v6,v7, y0,y1,y2,y3,y4,y5,y6,y7;
        {
            const float4* pv = (const float4*)&W_hh2[r0 * HH];
            v0=pv[0]; v1=pv[1]; v2=pv[2]; v3=pv[3];
            v4=pv[4]; v5=pv[5]; v6=pv[6]; v7=pv[7];
            const float4* py = (const float4*)&W_hh2[r1 * HH];
            y0=py[0]; y1=py[1]; y2=py[2]; y3=py[3];
            y4=py[4]; y5=py[5]; y6=py[6]; y7=py[7];
        }
        const float bias20 = b_ih2[r0] + b_hh2[r0];
        const float bias21 = b_ih2[r1] + b_hh2[r1];
        float c2 = 0.0f;
        float* h2out = h2_all + (long)b * SEQ * HH;
        int l1cache = 0;

        for (int s = 0; s < SEQ; ++s) {
            // wait for h1(s): one poll covers ~RING-lag future steps (cached)
            const int need = s + 1;
            while (l1cache < need) {
                l1cache = vfl[0];
                if (l1cache >= need) break;
                __builtin_amdgcn_s_sleep(1);
            }
            asm volatile("" ::: "memory");

            const float4* h1v = (const float4*)h1ring[s & (RING - 1)];
            const float4* h2v = (const float4*)h2buf[(s + 1) & 1];

            // e = W_ih2 (LDS, conflict-free) . h1(s);  p = W_hh2 (regs) . h2(s-1)
            float ea0=0.f,ea1=0.f,ea2=0.f,ea3=0.f, eb0=0.f,eb1=0.f,eb2=0.f,eb3=0.f;
            float pa0=0.f,pa1=0.f,pa2=0.f,pa3=0.f, pb0=0.f,pb1=0.f,pb2=0.f,pb3=0.f;
            float4 hq, wq;
            hq=h1v[0]; wq=T2[0*128+r0]; FMA4F(ea0,wq,hq); wq=T2[0*128+r1]; FMA4F(eb0,wq,hq);
            hq=h1v[1]; wq=T2[1*128+r0]; FMA4F(ea1,wq,hq); wq=T2[1*128+r1]; FMA4F(eb1,wq,hq);
            hq=h1v[2]; wq=T2[2*128+r0]; FMA4F(ea2,wq,hq); wq=T2[2*128+r1]; FMA4F(eb2,wq,hq);
            hq=h1v[3]; wq=T2[3*128+r0]; FMA4F(ea3,wq,hq); wq=T2[3*128+r1]; FMA4F(eb3,wq,hq);
            hq=h1v[4]; wq=T2[4*128+r0]; FMA4F(ea0,wq,hq); wq=T2[4*128+r1]; FMA4F(eb0,wq,hq);
            hq=h1v[5]; wq=T2[5*128+r0]; FMA4F(ea1,wq,hq); wq=T2[5*128+r1]; FMA4F(eb1,wq,hq);
            hq=h1v[6]; wq=T2[6*128+r0]; FMA4F(ea2,wq,hq); wq=T2[6*128+r1]; FMA4F(eb2,wq,hq);
            hq=h1v[7]; wq=T2[7*128+r0]; FMA4F(ea3,wq,hq); wq=T2[7*128+r1]; FMA4F(eb3,wq,hq);
            hq=h2v[0]; FMA4F(pa0,v0,hq); FMA4F(pb0,y0,hq);
            hq=h2v[1]; FMA4F(pa1,v1,hq); FMA4F(pb1,y1,hq);
            hq=h2v[2]; FMA4F(pa2,v2,hq); FMA4F(pb2,y2,hq);
            hq=h2v[3]; FMA4F(pa3,v3,hq); FMA4F(pb3,y3,hq);
            hq=h2v[4]; FMA4F(pa0,v4,hq); FMA4F(pb0,y4,hq);
            hq=h2v[5]; FMA4F(pa1,v5,hq); FMA4F(pb1,y5,hq);
            hq=h2v[6]; FMA4F(pa2,v6,hq); FMA4F(pb2,y6,hq);
            hq=h2v[7]; FMA4F(pa3,v7,hq); FMA4F(pb3,y7,hq);
            const float e0 = (ea0 + ea1) + (ea2 + ea3);
            const float e1 = (eb0 + eb1) + (eb2 + eb3);
            const float p0 = (pa0 + pa1) + (pa2 + pa3);
            const float p1 = (pb0 + pb1) + (pb2 + pb3);
            const float qr0 = bias20 + p0 + e0;
            const float qr1 = bias21 + p1 + e1;

            const float C0 = fsigm(qr0);
            const float C1 = 1.0f - c1p * __builtin_amdgcn_rcpf(1.0f + __expf(a1 * qr1));
            const float D0 = lane_xor32(C0, half);
            const float D1 = lane_xor32(C1, half);
            const float pi = half ? D0 : C0;
            const float pf = half ? C0 : D0;
            const float pg = half ? D1 : C1;
            const float po = half ? C1 : D1;

            c2 = pf * c2 + pi * pg;
            const float h2n = po * ftanh(c2);

            if (l < HH) {
                h2buf[s & 1][l] = h2n;
                h2out[(long)s * HH + l] = h2n;
            }
            asm volatile("s_waitcnt lgkmcnt(0)" ::: "memory");
            if (l == 0) vfl[1] = s + 1;
        }
    }
}

// ---------------------------------------------------------------------------
// Kernel C: logits = h2 @ W_fc^T + b_fc, row softmax, write [B*S][V].
// r1/r11-proven config: 8 rows/block, 256 threads, 8 vocab cols/thread.
// ---------------------------------------------------------------------------
__global__ __launch_bounds__(256) void fc_softmax_kernel(
    const float* __restrict__ h2_all, const float* __restrict__ W_fcT,
    const float* __restrict__ b_fc, float* __restrict__ out)
{
    const int tid = threadIdx.x;
    const long rowbase = (long)blockIdx.x * 8;
    __shared__ __align__(16) float h2t[8][HH];
    __shared__ float wred[8][4];

    h2t[tid >> 5][tid & 31] = h2_all[rowbase * HH + tid];
    __syncthreads();

    const int v0 = tid * 8;
    const float4 bf0 = *(const float4*)&b_fc[v0];
    const float4 bf1 = *(const float4*)&b_fc[v0 + 4];
    float acc[8][8];
#pragma unroll
    for (int r = 0; r < 8; ++r) {
        acc[r][0] = bf0.x; acc[r][1] = bf0.y; acc[r][2] = bf0.z; acc[r][3] = bf0.w;
        acc[r][4] = bf1.x; acc[r][5] = bf1.y; acc[r][6] = bf1.z; acc[r][7] = bf1.w;
    }

#pragma unroll
    for (int kq = 0; kq < 8; ++kq) {
        const int k = kq * 4;
        float4 wa[4], wb[4];
#pragma unroll
        for (int i = 0; i < 4; ++i) {
            wa[i] = *(const float4*)&W_fcT[(k + i) * VV + v0];
            wb[i] = *(const float4*)&W_fcT[(k + i) * VV + v0 + 4];
        }
#pragma unroll
        for (int r = 0; r < 8; ++r) {
            const float4 h = *(const float4*)&h2t[r][k];
            const float hh[4] = {h.x, h.y, h.z, h.w};
#pragma unroll
            for (int i = 0; i < 4; ++i) {
                acc[r][0] += hh[i] * wa[i].x; acc[r][1] += hh[i] * wa[i].y;
                acc[r][2] += hh[i] * wa[i].z; acc[r][3] += hh[i] * wa[i].w;
                acc[r][4] += hh[i] * wb[i].x; acc[r][5] += hh[i] * wb[i].y;
                acc[r][6] += hh[i] * wb[i].z; acc[r][7] += hh[i] * wb[i].w;
            }
        }
    }

    const int wv = tid >> 6;
    const int lane = tid & 63;

    float m[8];
#pragma unroll
    for (int r = 0; r < 8; ++r) {
        float v = acc[r][0];
#pragma unroll
        for (int c = 1; c < 8; ++c) v = fmaxf(v, acc[r][c]);
#pragma unroll
        for (int s = 32; s >= 1; s >>= 1) v = fmaxf(v, __shfl_xor(v, s, 64));
        m[r] = v;
    }
    if (lane == 0) {
#pragma unroll
        for (int r = 0; r < 8; ++r) wred[r][wv] = m[r];
    }
    __syncthreads();
    float rm[8];
#pragma unroll
    for (int r = 0; r < 8; ++r)
        rm[r] = fmaxf(fmaxf(wred[r][0], wred[r][1]), fmaxf(wred[r][2], wred[r][3]));
    __syncthreads();

    float s[8];
#pragma unroll
    for (int r = 0; r < 8; ++r) {
        float sum = 0.0f;
#pragma unroll
        for (int c = 0; c < 8; ++c) {
            float e = __expf(acc[r][c] - rm[r]);
            acc[r][c] = e;
            sum += e;
        }
#pragma unroll
        for (int st = 32; st >= 1; st >>= 1) sum += __shfl_xor(sum, st, 64);
        s[r] = sum;
    }
    if (lane == 0) {
#pragma unroll
        for (int r = 0; r < 8; ++r) wred[r][wv] = s[r];
    }
    __syncthreads();

#pragma unroll
    for (int r = 0; r < 8; ++r) {
        const float rs = wred[r][0] + wred[r][1] + wred[r][2] + wred[r][3];
        const float inv = 1.0f / rs;
        float4 o0 = make_float4(acc[r][0] * inv, acc[r][1] * inv, acc[r][2] * inv, acc[r][3] * inv);
        float4 o1 = make_float4(acc[r][4] * inv, acc[r][5] * inv, acc[r][6] * inv, acc[r][7] * inv);
        float* op = out + (rowbase + r) * VV + v0;
        *(float4*)op = o0;
        *(float4*)(op + 4) = o1;
    }
}

// ---------------------------------------------------------------------------
extern "C" void kernel_launch(void* const* d_in, const int* in_sizes, int n_in,
                              void* d_out, int out_size, void* d_ws, size_t ws_size,
                              hipStream_t stream)
{
    const int*   x_ids = (const int*)d_in[0];
    const float* emb   = (const float*)d_in[1];
    const float* W_ih1 = (const float*)d_in[2];
    const float* W_hh1 = (const float*)d_in[3];
    const float* b_ih1 = (const float*)d_in[4];
    const float* b_hh1 = (const float*)d_in[5];
    const float* W_ih2 = (const float*)d_in[6];
    const float* W_hh2 = (const float*)d_in[7];
    const float* b_ih2 = (const float*)d_in[8];
    const float* b_hh2 = (const float*)d_in[9];
    const float* W_fc  = (const float*)d_in[10];
    const float* b_fc  = (const float*)d_in[11];
    float* out = (float*)d_out;

    float* ws = (float*)d_ws;
    float* emb_proj = ws;                         // V*4H   = 262144
    float* W_fcT    = ws + 262144;                // H*V    = 65536
    float* h2_all   = ws + 262144 + 65536;        // B*S*H  = 2097152

    emb_proj_kernel<<<VV, 128, 0, stream>>>(emb, W_ih1, b_ih1, b_hh1, emb_proj);
    transpose_wfc_kernel<<<(VV * HH) / 256, 256, 0, stream>>>(W_fc, W_fcT);
    lstm_rec_pc_kernel<<<BB, 128, 0, stream>>>(x_ids, emb_proj, W_hh1, W_ih2, W_hh2,
                                               b_ih2, b_hh2, h2_all);
    fc_softmax_kernel<<<(BB * SEQ) / 8, 256, 0, stream>>>(h2_all, W_fcT, b_fc, out);
}